// Round 2
// baseline (222.261 us; speedup 1.0000x reference)
//
#include <hip/hip_runtime.h>
#include <hip/hip_fp16.h>

#define TSTEPS 4
#define DIM 32
#define NB 256
#define GROWS 128             // GEMM rows per block

// load 4 consecutive halfs (8B, aligned) -> float4
__device__ __forceinline__ float4 ldx4h(const __half* p) {
    uint2 u = *(const uint2*)p;
    __half2 h0 = *(__half2*)&u.x;
    __half2 h1 = *(__half2*)&u.y;
    float2 a = __half22float2(h0);
    float2 b = __half22float2(h1);
    return make_float4(a.x, a.y, b.x, b.y);
}

// ---- K1: per-node degree histogram (direct global atomics, L2-resident) ----
__global__ __launch_bounds__(256) void deg_kernel(
    const int* __restrict__ ei, int* __restrict__ deg, int E) {
    int stride = gridDim.x * 256;
    for (int e = blockIdx.x * 256 + threadIdx.x; e < E; e += stride)
        atomicAdd(&deg[ei[E + e]], 1);
}

// ---- K2: per-node CSR offsets. 256 nodes/block: in-block scan of 4-padded
// degrees; block base from one global cursor (bin placement order is
// nondeterministic but only relocates bins -> results identical). ----
__global__ __launch_bounds__(256) void offs_kernel(
    const int* __restrict__ deg, int* __restrict__ offs,
    float* __restrict__ dinv, int* __restrict__ cursor0, int N) {
    __shared__ int sc[NB];
    __shared__ int s_base;
    int tid = threadIdx.x;
    int n = (blockIdx.x << 8) + tid;
    int d = (n < N) ? deg[n] : 0;
    int padded = (d + 3) & ~3;
    sc[tid] = padded;
    __syncthreads();
    for (int off = 1; off < 256; off <<= 1) {
        int t = (tid >= off) ? sc[tid - off] : 0;
        __syncthreads();
        sc[tid] += t;
        __syncthreads();
    }
    if (tid == 255) s_base = atomicAdd(cursor0, sc[255]);
    __syncthreads();
    if (n < N) {
        offs[n] = s_base + sc[tid] - padded;   // multiple of 4 (int4-aligned)
        dinv[n] = rsqrtf((float)d + 1.0f);
    }
}

// ---- K3: fused edge scatter (blocks [0,scBlocks)) + GEMM (rest).
// Both roles are short and high-TLP, so fusion behaves like max(), and the
// GEMM (~10us, no deps) hides the scatter's atomic latency. ----
__global__ __launch_bounds__(256) void scattergemm_kernel(
    const int* __restrict__ ei, const int* __restrict__ offs,
    int* __restrict__ cur, int* __restrict__ rec,
    const float* __restrict__ s, const float* __restrict__ W,
    __half* __restrict__ xwp, int E, int rows, int N, int scBlocks) {
    __shared__ __align__(16) char smem[22528];
    int tid = threadIdx.x;

    if ((int)blockIdx.x < scBlocks) {
        int e = blockIdx.x * 256 + tid;
        if (e < E) {
            int src = ei[e];
            int dst = ei[E + e];
            int p = atomicAdd(&cur[dst], 1);
            rec[offs[dst] + p] = src;
        }
        return;
    }

    // ---- GEMM role: 128 rows/block, register-tiled (proven) ----
    float4 (*sW4)[8] = (float4 (*)[8])smem;            // 4 KB
    float  (*sS)[36] = (float (*)[36])(smem + 4096);   // 18.4 KB
    int row = tid >> 3;
    int cg  = tid & 7;
    sW4[row][cg] = ((const float4*)W)[tid];   // tid = k*8+cg exactly
    int rowBase = ((int)blockIdx.x - scBlocks) * GROWS;
#pragma unroll
    for (int j = 0; j < 4; j++) {
        int r = rowBase + row + j * 32;
        float4 sv = (r < rows) ? ((const float4*)s)[(size_t)r * 8 + cg]
                               : make_float4(0.f, 0.f, 0.f, 0.f);
        *(float4*)&sS[row + j * 32][cg * 4] = sv;
    }
    __syncthreads();
    float4 a0 = make_float4(0.f, 0.f, 0.f, 0.f);
    float4 a1 = a0, a2 = a0, a3 = a0;
#pragma unroll
    for (int k = 0; k < 32; k++) {
        float4 wv = sW4[k][cg];
        float s0 = sS[row][k];
        float s1 = sS[row + 32][k];
        float s2 = sS[row + 64][k];
        float s3 = sS[row + 96][k];
        a0.x += s0 * wv.x; a0.y += s0 * wv.y; a0.z += s0 * wv.z; a0.w += s0 * wv.w;
        a1.x += s1 * wv.x; a1.y += s1 * wv.y; a1.z += s1 * wv.z; a1.w += s1 * wv.w;
        a2.x += s2 * wv.x; a2.y += s2 * wv.y; a2.z += s2 * wv.z; a2.w += s2 * wv.w;
        a3.x += s3 * wv.x; a3.y += s3 * wv.y; a3.z += s3 * wv.z; a3.w += s3 * wv.w;
    }
    float4 accs[4] = {a0, a1, a2, a3};
#pragma unroll
    for (int j = 0; j < 4; j++) {
        int r = rowBase + row + j * 32;
        if (r < rows) {
            int t = r / N;
            int n = r - t * N;
            __half2 h0 = __floats2half2_rn(accs[j].x, accs[j].y);
            __half2 h1 = __floats2half2_rn(accs[j].z, accs[j].w);
            uint2 u;
            u.x = *(unsigned int*)&h0;
            u.y = *(unsigned int*)&h1;
            *(uint2*)(xwp + (size_t)n * 128 + t * 32 + cg * 4) = u;
        }
    }
}

// ---- K4: fused gather (fp16 xwp, unroll-8) + self-loop + mean + IF + z_new ----
__global__ __launch_bounds__(256) void gather_kernel(
    const int* __restrict__ rec, const int* __restrict__ offs,
    const int* __restrict__ deg, const __half* __restrict__ xwp,
    const float* __restrict__ dinv, const float* __restrict__ z,
    float* __restrict__ out, int N) {
    int gid = blockIdx.x * 256 + threadIdx.x;
    int n = gid >> 5;
    if (n >= N) return;
    int wl = threadIdx.x & 63;
    int half_ = wl >> 5;
    int l = wl & 31;
    int q = l & 7;
    long lofs = l * 4;   // offset in halfs (8B per lane)

    float dn = dinv[n];
    int beg = offs[n];       // multiple of 4 -> int4-aligned
    int cntn = deg[n];

    float4 acc = make_float4(0.f, 0.f, 0.f, 0.f);
    int i = 0;
    for (; i + 8 <= cntn; i += 8) {
        int4 sa = *(const int4*)(rec + beg + i);
        int4 sb = *(const int4*)(rec + beg + i + 4);
        float n0 = dinv[sa.x] * dn, n1 = dinv[sa.y] * dn;
        float n2 = dinv[sa.z] * dn, n3 = dinv[sa.w] * dn;
        float n4 = dinv[sb.x] * dn, n5 = dinv[sb.y] * dn;
        float n6 = dinv[sb.z] * dn, n7 = dinv[sb.w] * dn;
        float4 p0 = ldx4h(xwp + (long)sa.x * 128 + lofs);
        float4 p1 = ldx4h(xwp + (long)sa.y * 128 + lofs);
        float4 p2 = ldx4h(xwp + (long)sa.z * 128 + lofs);
        float4 p3 = ldx4h(xwp + (long)sa.w * 128 + lofs);
        float4 p4 = ldx4h(xwp + (long)sb.x * 128 + lofs);
        float4 p5 = ldx4h(xwp + (long)sb.y * 128 + lofs);
        float4 p6 = ldx4h(xwp + (long)sb.z * 128 + lofs);
        float4 p7 = ldx4h(xwp + (long)sb.w * 128 + lofs);
        acc.x += n0 * p0.x + n1 * p1.x + n2 * p2.x + n3 * p3.x
               + n4 * p4.x + n5 * p5.x + n6 * p6.x + n7 * p7.x;
        acc.y += n0 * p0.y + n1 * p1.y + n2 * p2.y + n3 * p3.y
               + n4 * p4.y + n5 * p5.y + n6 * p6.y + n7 * p7.y;
        acc.z += n0 * p0.z + n1 * p1.z + n2 * p2.z + n3 * p3.z
               + n4 * p4.z + n5 * p5.z + n6 * p6.z + n7 * p7.z;
        acc.w += n0 * p0.w + n1 * p1.w + n2 * p2.w + n3 * p3.w
               + n4 * p4.w + n5 * p5.w + n6 * p6.w + n7 * p7.w;
    }
    for (; i < cntn; i += 4) {
        int4 s4 = *(const int4*)(rec + beg + i);
        int rem = cntn - i;
        int i0 = s4.x;
        int i1 = (rem > 1) ? s4.y : i0;
        int i2 = (rem > 2) ? s4.z : i0;
        int i3 = (rem > 3) ? s4.w : i0;
        float n0 = dinv[i0] * dn;
        float n1 = (rem > 1) ? dinv[i1] * dn : 0.f;
        float n2 = (rem > 2) ? dinv[i2] * dn : 0.f;
        float n3 = (rem > 3) ? dinv[i3] * dn : 0.f;
        float4 p0 = ldx4h(xwp + (long)i0 * 128 + lofs);
        float4 p1 = ldx4h(xwp + (long)i1 * 128 + lofs);
        float4 p2 = ldx4h(xwp + (long)i2 * 128 + lofs);
        float4 p3 = ldx4h(xwp + (long)i3 * 128 + lofs);
        acc.x += n0 * p0.x + n1 * p1.x + n2 * p2.x + n3 * p3.x;
        acc.y += n0 * p0.y + n1 * p1.y + n2 * p2.y + n3 * p3.y;
        acc.z += n0 * p0.z + n1 * p1.z + n2 * p2.z + n3 * p3.z;
        acc.w += n0 * p0.w + n1 * p1.w + n2 * p2.w + n3 * p3.w;
    }
    // self loop
    {
        float d2 = dn * dn;
        float4 ps = ldx4h(xwp + (long)n * 128 + lofs);
        acc.x += d2 * ps.x;
        acc.y += d2 * ps.y;
        acc.z += d2 * ps.z;
        acc.w += d2 * ps.w;
    }
    // transpose (t,q) -> lane q holds x[t] for its 4 features
    float4 xs[TSTEPS];
#pragma unroll
    for (int t = 0; t < TSTEPS; t++) {
        int srcLane = half_ * 32 + t * 8 + q;
        xs[t].x = __shfl(acc.x, srcLane, 64);
        xs[t].y = __shfl(acc.y, srcLane, 64);
        xs[t].z = __shfl(acc.z, srcLane, 64);
        xs[t].w = __shfl(acc.w, srcLane, 64);
    }
    if (l < 8) {
        float4 y;
        y.x = (xs[0].x + xs[1].x + xs[2].x + xs[3].x) * 0.25f;
        y.y = (xs[0].y + xs[1].y + xs[2].y + xs[3].y) * 0.25f;
        y.z = (xs[0].z + xs[1].z + xs[2].z + xs[3].z) * 0.25f;
        y.w = (xs[0].w + xs[1].w + xs[2].w + xs[3].w) * 0.25f;
        float4 v = make_float4(0.f, 0.f, 0.f, 0.f);
        int colBase = n * 32 + q * 4;
#pragma unroll
        for (int t = 0; t < TSTEPS; t++) {
            float4 o;
            v.x += xs[t].x; o.x = (v.x >= 1.0f) ? 1.0f : 0.0f; v.x -= o.x;
            v.y += xs[t].y; o.y = (v.y >= 1.0f) ? 1.0f : 0.0f; v.y -= o.y;
            v.z += xs[t].z; o.z = (v.z >= 1.0f) ? 1.0f : 0.0f; v.z -= o.z;
            v.w += xs[t].w; o.w = (v.w >= 1.0f) ? 1.0f : 0.0f; v.w -= o.w;
            *(float4*)(out + (size_t)t * N * 32 + colBase) = o;
        }
        float4 zv = *(const float4*)(z + colBase);
        float4 zn;
        zn.x = zv.x + y.x;
        zn.y = zv.y + y.y;
        zn.z = zv.z + y.z;
        zn.w = zv.w + y.w;
        *(float4*)(out + (size_t)TSTEPS * N * 32 + colBase) = zn;
    }
}

extern "C" void kernel_launch(void* const* d_in, const int* in_sizes, int n_in,
                              void* d_out, int out_size, void* d_ws, size_t ws_size,
                              hipStream_t stream) {
    const float* s_seq = (const float*)d_in[0];
    const float* z_seq = (const float*)d_in[1];
    const float* W     = (const float*)d_in[2];
    const int*   ei    = (const int*)d_in[3];
    float* out = (float*)d_out;

    int N = in_sizes[1] / DIM;   // 50000
    int E = in_sizes[3] / 2;     // 800000
    int rows = TSTEPS * N;       // 200000
    int nbin = (N + 255) >> 8;   // 196 (offs blocks)

    // ws layout: xwp(fp16) | rec | offs | dinv | deg | cur | cursor0
    // (deg, cur, cursor0 contiguous -> single memset)
    char* w = (char*)d_ws;
    __half* xwp = (__half*)w;  w += (size_t)rows * DIM * 2;          // 12.8 MB
    int*   rec  = (int*)w;     w += ((size_t)E + 4 * (size_t)N + 64) * 4;  // 4.0 MB
    int*   offs = (int*)w;     w += (size_t)N * 4;
    float* dinv = (float*)w;   w += (size_t)N * 4;
    int*   deg  = (int*)w;     w += (size_t)N * 4;
    int*   cur  = (int*)w;     w += (size_t)N * 4;
    int*   cursor0 = (int*)w;  w += 64;

    hipMemsetAsync(deg, 0, ((size_t)2 * N + 16) * 4, stream);  // deg+cur+cursor0

    int scBlocks = (E + 255) / 256;              // 3125
    int xwBlocks = (rows + GROWS - 1) / GROWS;   // 1563

    deg_kernel<<<512, 256, 0, stream>>>(ei, deg, E);
    offs_kernel<<<nbin, 256, 0, stream>>>(deg, offs, dinv, cursor0, N);
    scattergemm_kernel<<<scBlocks + xwBlocks, 256, 0, stream>>>(
        ei, offs, cur, rec, s_seq, W, xwp, E, rows, N, scBlocks);
    gather_kernel<<<(N * 32 + 255) / 256, 256, 0, stream>>>(rec, offs, deg, xwp,
                                                            dinv, z_seq, out, N);
}

// Round 3
// 170.224 us; speedup vs baseline: 1.3057x; 1.3057x over previous
//
#include <hip/hip_runtime.h>
#include <hip/hip_fp16.h>

#define TSTEPS 4
#define DIM 32
#define BINW_SHIFT 8          // 256 nodes per coarse bin
#define NB 256                // bins (actual 196, rest zero)
#define GROWS 128             // GEMM rows per block
#define SP_CH 2048            // edges per chunk (hist & split use same chunking)
#define PAD_PER_BIN 772       // worst-case rec padding per bin (256*3 + 4)

// load 4 consecutive halfs (8B, aligned) -> float4
__device__ __forceinline__ float4 ldx4h(const __half* p) {
    uint2 u = *(const uint2*)p;
    __half2 h0 = *(__half2*)&u.x;
    __half2 h1 = *(__half2*)&u.y;
    float2 a = __half22float2(h0);
    float2 b = __half22float2(h1);
    return make_float4(a.x, a.y, b.x, b.y);
}

// ---- K1: per-chunk coarse histogram (blocks [0,nchunks)) + fused GEMM ----
__global__ __launch_bounds__(256) void histgemm_kernel(
    const int* __restrict__ ei, int* __restrict__ ghist,
    const float* __restrict__ s, const float* __restrict__ W,
    __half* __restrict__ xwp, int E, int rows, int N, int nchunks) {
    __shared__ __align__(16) char smem[22528];
    int tid = threadIdx.x;

    if ((int)blockIdx.x < nchunks) {
        int* lh = (int*)smem;
        lh[tid] = 0;
        __syncthreads();
        int beg = blockIdx.x * SP_CH;
        int end = min(beg + SP_CH, E);
        for (int e = beg + tid; e < end; e += 256)
            atomicAdd(&lh[ei[E + e] >> BINW_SHIFT], 1);
        __syncthreads();
        ghist[(size_t)blockIdx.x * NB + tid] = lh[tid];
        return;
    }

    // ---- GEMM role: 128 rows/block, register-tiled (proven) ----
    float4 (*sW4)[8] = (float4 (*)[8])smem;            // 4 KB
    float  (*sS)[36] = (float (*)[36])(smem + 4096);   // 18.4 KB
    int row = tid >> 3;
    int cg  = tid & 7;
    sW4[row][cg] = ((const float4*)W)[tid];   // tid = k*8+cg exactly
    int rowBase = ((int)blockIdx.x - nchunks) * GROWS;
#pragma unroll
    for (int j = 0; j < 4; j++) {
        int r = rowBase + row + j * 32;
        float4 sv = (r < rows) ? ((const float4*)s)[(size_t)r * 8 + cg]
                               : make_float4(0.f, 0.f, 0.f, 0.f);
        *(float4*)&sS[row + j * 32][cg * 4] = sv;
    }
    __syncthreads();
    float4 a0 = make_float4(0.f, 0.f, 0.f, 0.f);
    float4 a1 = a0, a2 = a0, a3 = a0;
#pragma unroll
    for (int k = 0; k < 32; k++) {
        float4 wv = sW4[k][cg];
        float s0 = sS[row][k];
        float s1 = sS[row + 32][k];
        float s2 = sS[row + 64][k];
        float s3 = sS[row + 96][k];
        a0.x += s0 * wv.x; a0.y += s0 * wv.y; a0.z += s0 * wv.z; a0.w += s0 * wv.w;
        a1.x += s1 * wv.x; a1.y += s1 * wv.y; a1.z += s1 * wv.z; a1.w += s1 * wv.w;
        a2.x += s2 * wv.x; a2.y += s2 * wv.y; a2.z += s2 * wv.z; a2.w += s2 * wv.w;
        a3.x += s3 * wv.x; a3.y += s3 * wv.y; a3.z += s3 * wv.z; a3.w += s3 * wv.w;
    }
    float4 accs[4] = {a0, a1, a2, a3};
#pragma unroll
    for (int j = 0; j < 4; j++) {
        int r = rowBase + row + j * 32;
        if (r < rows) {
            int t = r / N;
            int n = r - t * N;
            __half2 h0 = __floats2half2_rn(accs[j].x, accs[j].y);
            __half2 h1 = __floats2half2_rn(accs[j].z, accs[j].w);
            uint2 u;
            u.x = *(unsigned int*)&h0;
            u.y = *(unsigned int*)&h1;
            *(uint2*)(xwp + (size_t)n * 128 + t * 32 + cg * 4) = u;
        }
    }
}

// ---- K2: transposed scan. Block b: exclusive scan over chunks of bin b's
// counts (1 load per thread, in-block scan) -> ghist2[r][b]; totals[b]. ----
__global__ __launch_bounds__(512) void colscan_kernel(
    const int* __restrict__ ghist, int* __restrict__ ghist2,
    int* __restrict__ totals, int nchunks) {
    __shared__ int sc[512];
    int t = threadIdx.x;
    int b = blockIdx.x;
    int v = (t < nchunks) ? ghist[(size_t)t * NB + b] : 0;
    sc[t] = v;
    __syncthreads();
    for (int off = 1; off < 512; off <<= 1) {
        int tv = (t >= off) ? sc[t - off] : 0;
        __syncthreads();
        sc[t] += tv;
        __syncthreads();
    }
    if (t < nchunks) ghist2[(size_t)t * NB + b] = sc[t] - v;   // exclusive
    if (t == 511) totals[b] = sc[511];
}

// ---- K3: split with exact precomputed bases. No global reduction, no cursor
// atomics, no local histogram pass (loads its own ghist row). One LDS-staged
// pass + coalesced copy-out. ----
__global__ __launch_bounds__(256) void split_kernel(
    const int* __restrict__ ei, const int* __restrict__ ghist,
    const int* __restrict__ ghist2, const int* __restrict__ totals,
    unsigned int* __restrict__ esorted, int E) {
    __shared__ int binB[NB], pscan[NB], gb[NB], pcur[NB];
    __shared__ unsigned int sbuf[SP_CH];
    int tid = threadIdx.x;
    int bid = blockIdx.x;

    int tot = totals[tid];
    binB[tid] = tot;
    __syncthreads();
    for (int off = 1; off < 256; off <<= 1) {
        int t = (tid >= off) ? binB[tid - off] : 0;
        __syncthreads();
        binB[tid] += t;
        __syncthreads();
    }
    int v = ghist[(size_t)bid * NB + tid];
    pscan[tid] = v;
    __syncthreads();
    for (int off = 1; off < 256; off <<= 1) {
        int t = (tid >= off) ? pscan[tid - off] : 0;
        __syncthreads();
        pscan[tid] += t;
        __syncthreads();
    }
    int pexcl = pscan[tid] - v;
    pscan[tid] = pexcl;
    pcur[tid] = pexcl;
    gb[tid] = (binB[tid] - tot) + ghist2[(size_t)bid * NB + tid] - pexcl;
    __syncthreads();

    int beg = bid * SP_CH;
    int end = min(beg + SP_CH, E);
    int cnt = end - beg;
    for (int e = beg + tid; e < end; e += 256) {
        int sx = ei[e];
        int dx = ei[E + e];
        unsigned int pk = (unsigned int)sx | ((unsigned int)dx << 16);
        int b = dx >> BINW_SHIFT;
        int p = atomicAdd(&pcur[b], 1);
        sbuf[p] = pk;
    }
    __syncthreads();
    for (int idx = tid; idx < cnt; idx += 256) {
        unsigned int e = sbuf[idx];
        int b = e >> 24;                 // dst>>8 (dst in bits 16..31)
        esorted[gb[b] + idx] = e;
    }
}

// ---- K4: per-bin exact CSR. Preamble = coalesced totals load + one scan. ----
__global__ __launch_bounds__(256) void csr_kernel(
    const int* __restrict__ totals, const unsigned int* __restrict__ esorted,
    int* __restrict__ rec, int* __restrict__ offs, int* __restrict__ deg,
    float* __restrict__ dinv, int N) {
    __shared__ int lh[NB], sc[NB], loff[NB], lcur[NB];
    __shared__ int s_ebeg, s_cnt;
    int bin = blockIdx.x;
    int tid = threadIdx.x;
    sc[tid] = totals[tid];
    lh[tid] = 0;
    __syncthreads();
    for (int off = 1; off < 256; off <<= 1) {
        int t = (tid >= off) ? sc[tid - off] : 0;
        __syncthreads();
        sc[tid] += t;
        __syncthreads();
    }
    if (tid == 0) {
        int e0 = bin ? sc[bin - 1] : 0;
        s_ebeg = e0;
        s_cnt = sc[bin] - e0;
    }
    __syncthreads();
    int ebeg = s_ebeg;
    int cnt = s_cnt;
    int gbase = ((ebeg + 3) & ~3) + PAD_PER_BIN * bin;
    for (int i = tid; i < cnt; i += 256)
        atomicAdd(&lh[(esorted[ebeg + i] >> 16) & 255], 1);
    __syncthreads();
    int padded = (lh[tid] + 3) & ~3;
    sc[tid] = padded;
    __syncthreads();
    for (int off = 1; off < 256; off <<= 1) {
        int t = (tid >= off) ? sc[tid - off] : 0;
        __syncthreads();
        sc[tid] += t;
        __syncthreads();
    }
    loff[tid] = sc[tid] - padded;
    lcur[tid] = 0;
    __syncthreads();
    for (int i = tid; i < cnt; i += 256) {
        unsigned int e = esorted[ebeg + i];
        int ln = (e >> 16) & 255;
        int p = atomicAdd(&lcur[ln], 1);
        rec[gbase + loff[ln] + p] = (int)(e & 0xFFFFu);
    }
    int n = (bin << BINW_SHIFT) + tid;
    if (n < N) {
        offs[n] = gbase + loff[tid];
        deg[n] = lh[tid];
        dinv[n] = rsqrtf((float)lh[tid] + 1.0f);
    }
}

// ---- K5: fused gather (fp16 xwp, unroll-8) + self-loop + mean + IF + z_new ----
__global__ __launch_bounds__(256) void gather_kernel(
    const int* __restrict__ rec, const int* __restrict__ offs,
    const int* __restrict__ deg, const __half* __restrict__ xwp,
    const float* __restrict__ dinv, const float* __restrict__ z,
    float* __restrict__ out, int N) {
    int gid = blockIdx.x * 256 + threadIdx.x;
    int n = gid >> 5;
    if (n >= N) return;
    int wl = threadIdx.x & 63;
    int half_ = wl >> 5;
    int l = wl & 31;
    int q = l & 7;
    long lofs = l * 4;   // offset in halfs (8B per lane)

    float dn = dinv[n];
    int beg = offs[n];       // multiple of 4 -> int4-aligned
    int cntn = deg[n];

    float4 acc = make_float4(0.f, 0.f, 0.f, 0.f);
    int i = 0;
    for (; i + 8 <= cntn; i += 8) {
        int4 sa = *(const int4*)(rec + beg + i);
        int4 sb = *(const int4*)(rec + beg + i + 4);
        float n0 = dinv[sa.x] * dn, n1 = dinv[sa.y] * dn;
        float n2 = dinv[sa.z] * dn, n3 = dinv[sa.w] * dn;
        float n4 = dinv[sb.x] * dn, n5 = dinv[sb.y] * dn;
        float n6 = dinv[sb.z] * dn, n7 = dinv[sb.w] * dn;
        float4 p0 = ldx4h(xwp + (long)sa.x * 128 + lofs);
        float4 p1 = ldx4h(xwp + (long)sa.y * 128 + lofs);
        float4 p2 = ldx4h(xwp + (long)sa.z * 128 + lofs);
        float4 p3 = ldx4h(xwp + (long)sa.w * 128 + lofs);
        float4 p4 = ldx4h(xwp + (long)sb.x * 128 + lofs);
        float4 p5 = ldx4h(xwp + (long)sb.y * 128 + lofs);
        float4 p6 = ldx4h(xwp + (long)sb.z * 128 + lofs);
        float4 p7 = ldx4h(xwp + (long)sb.w * 128 + lofs);
        acc.x += n0 * p0.x + n1 * p1.x + n2 * p2.x + n3 * p3.x
               + n4 * p4.x + n5 * p5.x + n6 * p6.x + n7 * p7.x;
        acc.y += n0 * p0.y + n1 * p1.y + n2 * p2.y + n3 * p3.y
               + n4 * p4.y + n5 * p5.y + n6 * p6.y + n7 * p7.y;
        acc.z += n0 * p0.z + n1 * p1.z + n2 * p2.z + n3 * p3.z
               + n4 * p4.z + n5 * p5.z + n6 * p6.z + n7 * p7.z;
        acc.w += n0 * p0.w + n1 * p1.w + n2 * p2.w + n3 * p3.w
               + n4 * p4.w + n5 * p5.w + n6 * p6.w + n7 * p7.w;
    }
    for (; i < cntn; i += 4) {
        int4 s4 = *(const int4*)(rec + beg + i);
        int rem = cntn - i;
        int i0 = s4.x;
        int i1 = (rem > 1) ? s4.y : i0;
        int i2 = (rem > 2) ? s4.z : i0;
        int i3 = (rem > 3) ? s4.w : i0;
        float n0 = dinv[i0] * dn;
        float n1 = (rem > 1) ? dinv[i1] * dn : 0.f;
        float n2 = (rem > 2) ? dinv[i2] * dn : 0.f;
        float n3 = (rem > 3) ? dinv[i3] * dn : 0.f;
        float4 p0 = ldx4h(xwp + (long)i0 * 128 + lofs);
        float4 p1 = ldx4h(xwp + (long)i1 * 128 + lofs);
        float4 p2 = ldx4h(xwp + (long)i2 * 128 + lofs);
        float4 p3 = ldx4h(xwp + (long)i3 * 128 + lofs);
        acc.x += n0 * p0.x + n1 * p1.x + n2 * p2.x + n3 * p3.x;
        acc.y += n0 * p0.y + n1 * p1.y + n2 * p2.y + n3 * p3.y;
        acc.z += n0 * p0.z + n1 * p1.z + n2 * p2.z + n3 * p3.z;
        acc.w += n0 * p0.w + n1 * p1.w + n2 * p2.w + n3 * p3.w;
    }
    // self loop
    {
        float d2 = dn * dn;
        float4 ps = ldx4h(xwp + (long)n * 128 + lofs);
        acc.x += d2 * ps.x;
        acc.y += d2 * ps.y;
        acc.z += d2 * ps.z;
        acc.w += d2 * ps.w;
    }
    // transpose (t,q) -> lane q holds x[t] for its 4 features
    float4 xs[TSTEPS];
#pragma unroll
    for (int t = 0; t < TSTEPS; t++) {
        int srcLane = half_ * 32 + t * 8 + q;
        xs[t].x = __shfl(acc.x, srcLane, 64);
        xs[t].y = __shfl(acc.y, srcLane, 64);
        xs[t].z = __shfl(acc.z, srcLane, 64);
        xs[t].w = __shfl(acc.w, srcLane, 64);
    }
    if (l < 8) {
        float4 y;
        y.x = (xs[0].x + xs[1].x + xs[2].x + xs[3].x) * 0.25f;
        y.y = (xs[0].y + xs[1].y + xs[2].y + xs[3].y) * 0.25f;
        y.z = (xs[0].z + xs[1].z + xs[2].z + xs[3].z) * 0.25f;
        y.w = (xs[0].w + xs[1].w + xs[2].w + xs[3].w) * 0.25f;
        float4 v = make_float4(0.f, 0.f, 0.f, 0.f);
        int colBase = n * 32 + q * 4;
#pragma unroll
        for (int t = 0; t < TSTEPS; t++) {
            float4 o;
            v.x += xs[t].x; o.x = (v.x >= 1.0f) ? 1.0f : 0.0f; v.x -= o.x;
            v.y += xs[t].y; o.y = (v.y >= 1.0f) ? 1.0f : 0.0f; v.y -= o.y;
            v.z += xs[t].z; o.z = (v.z >= 1.0f) ? 1.0f : 0.0f; v.z -= o.z;
            v.w += xs[t].w; o.w = (v.w >= 1.0f) ? 1.0f : 0.0f; v.w -= o.w;
            *(float4*)(out + (size_t)t * N * 32 + colBase) = o;
        }
        float4 zv = *(const float4*)(z + colBase);
        float4 zn;
        zn.x = zv.x + y.x;
        zn.y = zv.y + y.y;
        zn.z = zv.z + y.z;
        zn.w = zv.w + y.w;
        *(float4*)(out + (size_t)TSTEPS * N * 32 + colBase) = zn;
    }
}

extern "C" void kernel_launch(void* const* d_in, const int* in_sizes, int n_in,
                              void* d_out, int out_size, void* d_ws, size_t ws_size,
                              hipStream_t stream) {
    const float* s_seq = (const float*)d_in[0];
    const float* z_seq = (const float*)d_in[1];
    const float* W     = (const float*)d_in[2];
    const int*   ei    = (const int*)d_in[3];
    float* out = (float*)d_out;

    int N = in_sizes[1] / DIM;   // 50000
    int E = in_sizes[3] / 2;     // 800000
    int rows = TSTEPS * N;       // 200000
    int nb = (N + 255) >> BINW_SHIFT;        // 196
    int nchunks = (E + SP_CH - 1) / SP_CH;   // 391

    // ws layout: xwp(fp16) | esorted(packed u32) | rec | offs | deg | dinv |
    //            ghist | ghist2 | totals    (no memset needed)
    char* w = (char*)d_ws;
    __half* xwp           = (__half*)w;       w += (size_t)rows * DIM * 2;   // 12.8 MB
    unsigned int* esorted = (unsigned int*)w; w += (size_t)E * 4;            // 3.2 MB
    int*   rec    = (int*)w;  w += ((size_t)E + PAD_PER_BIN * nb + 16) * 4;  // 3.8 MB
    int*   offs   = (int*)w;  w += (size_t)N * 4;
    int*   deg    = (int*)w;  w += (size_t)N * 4;
    float* dinv   = (float*)w; w += (size_t)N * 4;
    int*   ghist  = (int*)w;  w += (size_t)nchunks * NB * 4;                 // 400 KB
    int*   ghist2 = (int*)w;  w += (size_t)nchunks * NB * 4;                 // 400 KB
    int*   totals = (int*)w;  w += NB * 4;

    int xwBlocks = (rows + GROWS - 1) / GROWS;   // 1563
    histgemm_kernel<<<nchunks + xwBlocks, 256, 0, stream>>>(
        ei, ghist, s_seq, W, xwp, E, rows, N, nchunks);
    colscan_kernel<<<NB, 512, 0, stream>>>(ghist, ghist2, totals, nchunks);
    split_kernel<<<nchunks, 256, 0, stream>>>(ei, ghist, ghist2, totals, esorted, E);
    csr_kernel<<<nb, 256, 0, stream>>>(totals, esorted, rec, offs, deg, dinv, N);
    gather_kernel<<<(N * 32 + 255) / 256, 256, 0, stream>>>(rec, offs, deg, xwp,
                                                            dinv, z_seq, out, N);
}

// Round 4
// 155.077 us; speedup vs baseline: 1.4332x; 1.0977x over previous
//
#include <hip/hip_runtime.h>
#include <hip/hip_fp16.h>

#define TSTEPS 4
#define DIM 32
#define BINW_SHIFT 8          // 256 nodes per coarse bin
#define NB 256                // bins (actual 196, rest zero)
#define SP_CH 2048            // edges per chunk (hist & split use same chunking)
#define PAD_PER_BIN 772       // worst-case rec padding per bin (256*3 + 4)

typedef _Float16 f16x8 __attribute__((ext_vector_type(8)));
typedef float f32x4 __attribute__((ext_vector_type(4)));

// load 4 consecutive halfs (8B, aligned) -> float4
__device__ __forceinline__ float4 ldx4h(const __half* p) {
    uint2 u = *(const uint2*)p;
    __half2 h0 = *(__half2*)&u.x;
    __half2 h1 = *(__half2*)&u.y;
    float2 a = __half22float2(h0);
    float2 b = __half22float2(h1);
    return make_float4(a.x, a.y, b.x, b.y);
}

// ---- K1: per-chunk coarse histogram (blocks [0,nchunks)) + MFMA GEMM ----
// GEMM: xw = s @ W via v_mfma_f32_16x16x32_f16 (K=32 in ONE mfma, no K-loop,
// no LDS staging of s, no dependent-LDS chain -> latency-robust).
// Block = 4 waves x 32 rows = 128 rows. B-frags built once from LDS-staged W.
__global__ __launch_bounds__(256) void histgemm_kernel(
    const int* __restrict__ ei, int* __restrict__ ghist,
    const float* __restrict__ s, const float* __restrict__ W,
    __half* __restrict__ xwp, int E, int rows, int N, int nchunks) {
    __shared__ float Wf[32][33];   // 4.2 KB; hist role reuses first 1 KB
    int tid = threadIdx.x;

    if ((int)blockIdx.x < nchunks) {
        int* lh = (int*)Wf;
        lh[tid] = 0;
        __syncthreads();
        int beg = blockIdx.x * SP_CH;
        int end = min(beg + SP_CH, E);
        for (int e = beg + tid; e < end; e += 256)
            atomicAdd(&lh[ei[E + e] >> BINW_SHIFT], 1);
        __syncthreads();
        ghist[(size_t)blockIdx.x * NB + tid] = lh[tid];
        return;
    }

    // ---- GEMM role ----
    {
        // stage W (f32, coalesced: 256 threads x float4 = 1024 floats exactly)
        float4 wv = ((const float4*)W)[tid];
        int kk = tid >> 3, c4 = (tid & 7) * 4;
        Wf[kk][c4 + 0] = wv.x; Wf[kk][c4 + 1] = wv.y;
        Wf[kk][c4 + 2] = wv.z; Wf[kk][c4 + 3] = wv.w;
    }
    __syncthreads();

    int lane = tid & 63;
    int wid  = tid >> 6;          // 0..3
    int lrow = lane & 15;         // A-row / B-col / D-col fragment index
    int kq   = lane >> 4;         // k-group 0..3
    int k0   = kq * 8;

    // B-frags (block-invariant): lane holds W[k0..k0+7][col], col = ct*16+lrow
    f16x8 b0, b1;
#pragma unroll
    for (int i = 0; i < 8; i++) {
        b0[i] = (_Float16)Wf[k0 + i][lrow];
        b1[i] = (_Float16)Wf[k0 + i][lrow + 16];
    }

    int rbase = ((int)blockIdx.x - nchunks) * 128 + wid * 32;
#pragma unroll
    for (int rt = 0; rt < 2; rt++) {
        int r = rbase + rt * 16 + lrow;
        f16x8 a;
        if (r < rows) {
            const float4* sp = (const float4*)(s + (size_t)r * 32 + k0);
            float4 u0 = sp[0], u1 = sp[1];
            a[0] = (_Float16)u0.x; a[1] = (_Float16)u0.y;
            a[2] = (_Float16)u0.z; a[3] = (_Float16)u0.w;
            a[4] = (_Float16)u1.x; a[5] = (_Float16)u1.y;
            a[6] = (_Float16)u1.z; a[7] = (_Float16)u1.w;
        } else {
#pragma unroll
            for (int i = 0; i < 8; i++) a[i] = (_Float16)0.f;
        }
        f32x4 c0 = {0.f, 0.f, 0.f, 0.f};
        f32x4 c1 = {0.f, 0.f, 0.f, 0.f};
        c0 = __builtin_amdgcn_mfma_f32_16x16x32_f16(a, b0, c0, 0, 0, 0);
        c1 = __builtin_amdgcn_mfma_f32_16x16x32_f16(a, b1, c1, 0, 0, 0);
        // D: col = lrow, row = kq*4 + reg
        int rr = rbase + rt * 16 + kq * 4;
#pragma unroll
        for (int reg = 0; reg < 4; reg++) {
            int r2 = rr + reg;
            if (r2 < rows) {
                int t = (r2 >= 3 * N) ? 3 : (r2 >= 2 * N) ? 2 : (r2 >= N) ? 1 : 0;
                int n = r2 - t * N;
                __half* dst = xwp + (size_t)n * 128 + t * 32;
                dst[lrow]      = __float2half(c0[reg]);
                dst[lrow + 16] = __float2half(c1[reg]);
            }
        }
    }
}

// ---- K2: transposed scan. Block b: exclusive scan over chunks of bin b's
// counts (1 load per thread, in-block scan) -> ghist2[r][b]; totals[b]. ----
__global__ __launch_bounds__(512) void colscan_kernel(
    const int* __restrict__ ghist, int* __restrict__ ghist2,
    int* __restrict__ totals, int nchunks) {
    __shared__ int sc[512];
    int t = threadIdx.x;
    int b = blockIdx.x;
    int v = (t < nchunks) ? ghist[(size_t)t * NB + b] : 0;
    sc[t] = v;
    __syncthreads();
    for (int off = 1; off < 512; off <<= 1) {
        int tv = (t >= off) ? sc[t - off] : 0;
        __syncthreads();
        sc[t] += tv;
        __syncthreads();
    }
    if (t < nchunks) ghist2[(size_t)t * NB + b] = sc[t] - v;   // exclusive
    if (t == 511) totals[b] = sc[511];
}

// ---- K3: split with exact precomputed bases. No global reduction, no cursor
// atomics, no local histogram pass (loads its own ghist row). One LDS-staged
// pass + coalesced copy-out. ----
__global__ __launch_bounds__(256) void split_kernel(
    const int* __restrict__ ei, const int* __restrict__ ghist,
    const int* __restrict__ ghist2, const int* __restrict__ totals,
    unsigned int* __restrict__ esorted, int E) {
    __shared__ int binB[NB], pscan[NB], gb[NB], pcur[NB];
    __shared__ unsigned int sbuf[SP_CH];
    int tid = threadIdx.x;
    int bid = blockIdx.x;

    int tot = totals[tid];
    binB[tid] = tot;
    __syncthreads();
    for (int off = 1; off < 256; off <<= 1) {
        int t = (tid >= off) ? binB[tid - off] : 0;
        __syncthreads();
        binB[tid] += t;
        __syncthreads();
    }
    int v = ghist[(size_t)bid * NB + tid];
    pscan[tid] = v;
    __syncthreads();
    for (int off = 1; off < 256; off <<= 1) {
        int t = (tid >= off) ? pscan[tid - off] : 0;
        __syncthreads();
        pscan[tid] += t;
        __syncthreads();
    }
    int pexcl = pscan[tid] - v;
    pscan[tid] = pexcl;
    pcur[tid] = pexcl;
    gb[tid] = (binB[tid] - tot) + ghist2[(size_t)bid * NB + tid] - pexcl;
    __syncthreads();

    int beg = bid * SP_CH;
    int end = min(beg + SP_CH, E);
    int cnt = end - beg;
    for (int e = beg + tid; e < end; e += 256) {
        int sx = ei[e];
        int dx = ei[E + e];
        unsigned int pk = (unsigned int)sx | ((unsigned int)dx << 16);
        int b = dx >> BINW_SHIFT;
        int p = atomicAdd(&pcur[b], 1);
        sbuf[p] = pk;
    }
    __syncthreads();
    for (int idx = tid; idx < cnt; idx += 256) {
        unsigned int e = sbuf[idx];
        int b = e >> 24;                 // dst>>8 (dst in bits 16..31)
        esorted[gb[b] + idx] = e;
    }
}

// ---- K4: per-bin exact CSR. Preamble = coalesced totals load + one scan. ----
__global__ __launch_bounds__(256) void csr_kernel(
    const int* __restrict__ totals, const unsigned int* __restrict__ esorted,
    int* __restrict__ rec, int* __restrict__ offs, int* __restrict__ deg,
    float* __restrict__ dinv, int N) {
    __shared__ int lh[NB], sc[NB], loff[NB], lcur[NB];
    __shared__ int s_ebeg, s_cnt;
    int bin = blockIdx.x;
    int tid = threadIdx.x;
    sc[tid] = totals[tid];
    lh[tid] = 0;
    __syncthreads();
    for (int off = 1; off < 256; off <<= 1) {
        int t = (tid >= off) ? sc[tid - off] : 0;
        __syncthreads();
        sc[tid] += t;
        __syncthreads();
    }
    if (tid == 0) {
        int e0 = bin ? sc[bin - 1] : 0;
        s_ebeg = e0;
        s_cnt = sc[bin] - e0;
    }
    __syncthreads();
    int ebeg = s_ebeg;
    int cnt = s_cnt;
    int gbase = ((ebeg + 3) & ~3) + PAD_PER_BIN * bin;
    for (int i = tid; i < cnt; i += 256)
        atomicAdd(&lh[(esorted[ebeg + i] >> 16) & 255], 1);
    __syncthreads();
    int padded = (lh[tid] + 3) & ~3;
    sc[tid] = padded;
    __syncthreads();
    for (int off = 1; off < 256; off <<= 1) {
        int t = (tid >= off) ? sc[tid - off] : 0;
        __syncthreads();
        sc[tid] += t;
        __syncthreads();
    }
    loff[tid] = sc[tid] - padded;
    lcur[tid] = 0;
    __syncthreads();
    for (int i = tid; i < cnt; i += 256) {
        unsigned int e = esorted[ebeg + i];
        int ln = (e >> 16) & 255;
        int p = atomicAdd(&lcur[ln], 1);
        rec[gbase + loff[ln] + p] = (int)(e & 0xFFFFu);
    }
    int n = (bin << BINW_SHIFT) + tid;
    if (n < N) {
        offs[n] = gbase + loff[tid];
        deg[n] = lh[tid];
        dinv[n] = rsqrtf((float)lh[tid] + 1.0f);
    }
}

// ---- K5: fused gather (fp16 xwp, unroll-8) + self-loop + mean + IF + z_new ----
__global__ __launch_bounds__(256) void gather_kernel(
    const int* __restrict__ rec, const int* __restrict__ offs,
    const int* __restrict__ deg, const __half* __restrict__ xwp,
    const float* __restrict__ dinv, const float* __restrict__ z,
    float* __restrict__ out, int N) {
    int gid = blockIdx.x * 256 + threadIdx.x;
    int n = gid >> 5;
    if (n >= N) return;
    int wl = threadIdx.x & 63;
    int half_ = wl >> 5;
    int l = wl & 31;
    int q = l & 7;
    long lofs = l * 4;   // offset in halfs (8B per lane)

    float dn = dinv[n];
    int beg = offs[n];       // multiple of 4 -> int4-aligned
    int cntn = deg[n];

    float4 acc = make_float4(0.f, 0.f, 0.f, 0.f);
    int i = 0;
    for (; i + 8 <= cntn; i += 8) {
        int4 sa = *(const int4*)(rec + beg + i);
        int4 sb = *(const int4*)(rec + beg + i + 4);
        float n0 = dinv[sa.x] * dn, n1 = dinv[sa.y] * dn;
        float n2 = dinv[sa.z] * dn, n3 = dinv[sa.w] * dn;
        float n4 = dinv[sb.x] * dn, n5 = dinv[sb.y] * dn;
        float n6 = dinv[sb.z] * dn, n7 = dinv[sb.w] * dn;
        float4 p0 = ldx4h(xwp + (long)sa.x * 128 + lofs);
        float4 p1 = ldx4h(xwp + (long)sa.y * 128 + lofs);
        float4 p2 = ldx4h(xwp + (long)sa.z * 128 + lofs);
        float4 p3 = ldx4h(xwp + (long)sa.w * 128 + lofs);
        float4 p4 = ldx4h(xwp + (long)sb.x * 128 + lofs);
        float4 p5 = ldx4h(xwp + (long)sb.y * 128 + lofs);
        float4 p6 = ldx4h(xwp + (long)sb.z * 128 + lofs);
        float4 p7 = ldx4h(xwp + (long)sb.w * 128 + lofs);
        acc.x += n0 * p0.x + n1 * p1.x + n2 * p2.x + n3 * p3.x
               + n4 * p4.x + n5 * p5.x + n6 * p6.x + n7 * p7.x;
        acc.y += n0 * p0.y + n1 * p1.y + n2 * p2.y + n3 * p3.y
               + n4 * p4.y + n5 * p5.y + n6 * p6.y + n7 * p7.y;
        acc.z += n0 * p0.z + n1 * p1.z + n2 * p2.z + n3 * p3.z
               + n4 * p4.z + n5 * p5.z + n6 * p6.z + n7 * p7.z;
        acc.w += n0 * p0.w + n1 * p1.w + n2 * p2.w + n3 * p3.w
               + n4 * p4.w + n5 * p5.w + n6 * p6.w + n7 * p7.w;
    }
    for (; i < cntn; i += 4) {
        int4 s4 = *(const int4*)(rec + beg + i);
        int rem = cntn - i;
        int i0 = s4.x;
        int i1 = (rem > 1) ? s4.y : i0;
        int i2 = (rem > 2) ? s4.z : i0;
        int i3 = (rem > 3) ? s4.w : i0;
        float n0 = dinv[i0] * dn;
        float n1 = (rem > 1) ? dinv[i1] * dn : 0.f;
        float n2 = (rem > 2) ? dinv[i2] * dn : 0.f;
        float n3 = (rem > 3) ? dinv[i3] * dn : 0.f;
        float4 p0 = ldx4h(xwp + (long)i0 * 128 + lofs);
        float4 p1 = ldx4h(xwp + (long)i1 * 128 + lofs);
        float4 p2 = ldx4h(xwp + (long)i2 * 128 + lofs);
        float4 p3 = ldx4h(xwp + (long)i3 * 128 + lofs);
        acc.x += n0 * p0.x + n1 * p1.x + n2 * p2.x + n3 * p3.x;
        acc.y += n0 * p0.y + n1 * p1.y + n2 * p2.y + n3 * p3.y;
        acc.z += n0 * p0.z + n1 * p1.z + n2 * p2.z + n3 * p3.z;
        acc.w += n0 * p0.w + n1 * p1.w + n2 * p2.w + n3 * p3.w;
    }
    // self loop
    {
        float d2 = dn * dn;
        float4 ps = ldx4h(xwp + (long)n * 128 + lofs);
        acc.x += d2 * ps.x;
        acc.y += d2 * ps.y;
        acc.z += d2 * ps.z;
        acc.w += d2 * ps.w;
    }
    // transpose (t,q) -> lane q holds x[t] for its 4 features
    float4 xs[TSTEPS];
#pragma unroll
    for (int t = 0; t < TSTEPS; t++) {
        int srcLane = half_ * 32 + t * 8 + q;
        xs[t].x = __shfl(acc.x, srcLane, 64);
        xs[t].y = __shfl(acc.y, srcLane, 64);
        xs[t].z = __shfl(acc.z, srcLane, 64);
        xs[t].w = __shfl(acc.w, srcLane, 64);
    }
    if (l < 8) {
        float4 y;
        y.x = (xs[0].x + xs[1].x + xs[2].x + xs[3].x) * 0.25f;
        y.y = (xs[0].y + xs[1].y + xs[2].y + xs[3].y) * 0.25f;
        y.z = (xs[0].z + xs[1].z + xs[2].z + xs[3].z) * 0.25f;
        y.w = (xs[0].w + xs[1].w + xs[2].w + xs[3].w) * 0.25f;
        float4 v = make_float4(0.f, 0.f, 0.f, 0.f);
        int colBase = n * 32 + q * 4;
#pragma unroll
        for (int t = 0; t < TSTEPS; t++) {
            float4 o;
            v.x += xs[t].x; o.x = (v.x >= 1.0f) ? 1.0f : 0.0f; v.x -= o.x;
            v.y += xs[t].y; o.y = (v.y >= 1.0f) ? 1.0f : 0.0f; v.y -= o.y;
            v.z += xs[t].z; o.z = (v.z >= 1.0f) ? 1.0f : 0.0f; v.z -= o.z;
            v.w += xs[t].w; o.w = (v.w >= 1.0f) ? 1.0f : 0.0f; v.w -= o.w;
            *(float4*)(out + (size_t)t * N * 32 + colBase) = o;
        }
        float4 zv = *(const float4*)(z + colBase);
        float4 zn;
        zn.x = zv.x + y.x;
        zn.y = zv.y + y.y;
        zn.z = zv.z + y.z;
        zn.w = zv.w + y.w;
        *(float4*)(out + (size_t)TSTEPS * N * 32 + colBase) = zn;
    }
}

extern "C" void kernel_launch(void* const* d_in, const int* in_sizes, int n_in,
                              void* d_out, int out_size, void* d_ws, size_t ws_size,
                              hipStream_t stream) {
    const float* s_seq = (const float*)d_in[0];
    const float* z_seq = (const float*)d_in[1];
    const float* W     = (const float*)d_in[2];
    const int*   ei    = (const int*)d_in[3];
    float* out = (float*)d_out;

    int N = in_sizes[1] / DIM;   // 50000
    int E = in_sizes[3] / 2;     // 800000
    int rows = TSTEPS * N;       // 200000
    int nb = (N + 255) >> BINW_SHIFT;        // 196
    int nchunks = (E + SP_CH - 1) / SP_CH;   // 391

    // ws layout: xwp(fp16) | esorted(packed u32) | rec | offs | deg | dinv |
    //            ghist | ghist2 | totals    (no memset needed)
    char* w = (char*)d_ws;
    __half* xwp           = (__half*)w;       w += (size_t)rows * DIM * 2;   // 12.8 MB
    unsigned int* esorted = (unsigned int*)w; w += (size_t)E * 4;            // 3.2 MB
    int*   rec    = (int*)w;  w += ((size_t)E + PAD_PER_BIN * nb + 16) * 4;  // 3.8 MB
    int*   offs   = (int*)w;  w += (size_t)N * 4;
    int*   deg    = (int*)w;  w += (size_t)N * 4;
    float* dinv   = (float*)w; w += (size_t)N * 4;
    int*   ghist  = (int*)w;  w += (size_t)nchunks * NB * 4;                 // 400 KB
    int*   ghist2 = (int*)w;  w += (size_t)nchunks * NB * 4;                 // 400 KB
    int*   totals = (int*)w;  w += NB * 4;

    int xwBlocks = (rows + 127) / 128;   // 1563
    histgemm_kernel<<<nchunks + xwBlocks, 256, 0, stream>>>(
        ei, ghist, s_seq, W, xwp, E, rows, N, nchunks);
    colscan_kernel<<<NB, 512, 0, stream>>>(ghist, ghist2, totals, nchunks);
    split_kernel<<<nchunks, 256, 0, stream>>>(ei, ghist, ghist2, totals, esorted, E);
    csr_kernel<<<nb, 256, 0, stream>>>(totals, esorted, rec, offs, deg, dinv, N);
    gather_kernel<<<(N * 32 + 255) / 256, 256, 0, stream>>>(rec, offs, deg, xwp,
                                                            dinv, z_seq, out, N);
}